// Round 8
// baseline (1014.139 us; speedup 1.0000x reference)
//
#include <hip/hip_runtime.h>
#include <hip/hip_bf16.h>

// GCLSTM: B=512, T=32, H=300, K=10. f32 in/out.
// R8 = R7 with cells ALSO on MFMA: wave w <-> neighbor k; per k the gate
// pre-activations are G[(half,b) 8][h 300] = X[8][11+bias] @ Wih_g[12][300],
// 3 gate accumulators per lane, transcendentals in-thread, D written straight
// into cct[n][h+300*half]. Scalar cells loop + WIHP/BCP tables deleted.
// kern_main per (t,btile): cells-MFMA -> wp-MFMA -> hcat -> F1-MFMA -> softmax.

#define TB 4
#define NTHR 640          // 10 waves
#define NW 10
#define KP 616

// ws layout (u32 slots)
#define OFF_SM    0         // softmax [32][10][512] f32          163840
#define OFF_WBF2  163840    // wp A-frags [mt19][ks19][lane64][4]  92416
#define OFF_F1S   256256    // F1 B-frags [nt13][ks19][lane64][4]  63232
#define OFF_WCELL 319488    // cells B-frags [k10][ht19][g3][lane64][4] 145920
#define OFF_BTP   465408    // g*300+h f32                           900
#define OFF_WTP   466308    // (e*3+g)*300+h f32                    3600
#define OFF_WA    469908    // softmax(DisM) f32                      10
#define OFF_SWA   469918    // sum(wA) f32                             1
#define BASE_U32  469920
#define CON1_BYTE ((size_t)BASE_U32 * 4)                  // 1,879,680
#define WS_MIN_BYTES (CON1_BYTE + (size_t)98304000)       // 100,183,680 (< proven 100,436,608)

typedef __attribute__((ext_vector_type(8))) short s16x8;
typedef __attribute__((ext_vector_type(4))) float f32x4;
typedef unsigned short u16;

__device__ __forceinline__ float sigf(float x){ return 1.0f/(1.0f+__expf(-x)); }
__device__ __forceinline__ float tanhf_(float x){ return 1.0f - 2.0f/(__expf(2.0f*x)+1.0f); }
__device__ __forceinline__ float bfu(u16 u){ return __uint_as_float(((unsigned)u)<<16); }
__device__ __forceinline__ u16 f2usr(float f){   // RNE bf16
  __hip_bfloat16 h = __float2bfloat16(f);
  return *(u16*)&h;
}

// ================= fused per-(t, b-tile) kernel, 10 waves =================
__global__ __launch_bounds__(NTHR,2) void kern_main(
    const float* __restrict__ li, const float* __restrict__ exs,
    const float* __restrict__ AngleM, const float* __restrict__ bp,
    const float* __restrict__ F2, const float* __restrict__ b2,
    const float* wsf, unsigned* __restrict__ con1u, float* smg)
{
  __shared__ __align__(16) u16 cct[48][KP];   // 59,136 B
  __shared__ float xs[2][TB][11][10];         //  3,520
  __shared__ float xse[TB][2][10];            //    320
  __shared__ float exss[TB][4];               //     64
  __shared__ float wdP[NW][48];               //  1,920
  __shared__ float wdL[48];                   //    192  (total 65,152 <= 65,536)
  const int tid = threadIdx.x;
  const int t = blockIdx.y, bt = blockIdx.x, b0 = bt*TB;
  const int w = tid>>6, lane = tid&63, lo = lane&15, qd = lane>>4;

  // ---- P0: stage inputs; zero cells K-pad cols [600,616) rows 0..39, rows 40..47 ----
  for (int p=tid; p<2*TB*110; p+=NTHR){
    int half=p/440, r=p%440, b=r/110, q=r%110, i=q/10, k=q%10;
    int tp = half ? (t>0? t-1 : 0) : t;
    xs[half][b][i][k] = li[(((b0+b)*32+tp)*28+i)*10+k];
  }
  for (int p=tid;p<TB*20;p+=NTHR){
    int b=p/20, r=p%20, rr=r/10, k=r%10;
    xse[b][rr][k] = li[(((b0+b)*32+t)*28 + (rr?10:8))*10 + k];
  }
  for (int p=tid;p<TB*4;p+=NTHR){
    int b=p/4, e=p%4;
    exss[b][e] = exs[((b0+b)*32+t)*4+e];
  }
  for (int p=tid; p<40*8; p+=NTHR){            // rows 0..39, cols 600..615 (8 u32)
    int n=p/8, c=p%8;
    ((unsigned*)&cct[n][600])[c] = 0u;
  }
  for (int p=tid; p<8*(KP/2); p+=NTHR){        // rows 40..47 full
    int n=40+p/(KP/2), c=p%(KP/2);
    ((unsigned*)&cct[n][0])[c] = 0u;
  }
  __syncthreads();

  // ---- P1: cells-MFMA, wave w = neighbor k ----
  // A[row=(half*4+b)][kk]: kk<11 = x[half][b][kk][w]; kk==11 = 1.0 (bias row)
  {
    short av[8];
    #pragma unroll
    for (int j=0;j<8;j++){
      int kk = qd*8+j;
      float v = 0.f;
      if (lo<8){
        if (kk<11) v = xs[lo>>2][lo&3][kk][w];
        else if (kk==11) v = 1.0f;
      }
      av[j] = (short)f2usr(v);
    }
    s16x8 Ax = (s16x8){av[0],av[1],av[2],av[3],av[4],av[5],av[6],av[7]};
    const u16* wcell = (const u16*)((const unsigned*)wsf + OFF_WCELL);
    for (int ht=0; ht<19; ht++){
      const u16* bb = wcell + ((size_t)(w*19+ht)*3)*512;   // 512 u16 per gate-frag
      s16x8 Bi = *(const s16x8*)(bb +    0 + lane*8);
      s16x8 Bg = *(const s16x8*)(bb +  512 + lane*8);
      s16x8 Bo = *(const s16x8*)(bb + 1024 + lane*8);
      f32x4 gi={0.f,0.f,0.f,0.f}, gg={0.f,0.f,0.f,0.f}, go={0.f,0.f,0.f,0.f};
      gi = __builtin_amdgcn_mfma_f32_16x16x32_bf16(Ax, Bi, gi, 0,0,0);
      gg = __builtin_amdgcn_mfma_f32_16x16x32_bf16(Ax, Bg, gg, 0,0,0);
      go = __builtin_amdgcn_mfma_f32_16x16x32_bf16(Ax, Bo, go, 0,0,0);
      int h = ht*16+lo;
      if (qd<2 && h<300){   // D row=qd*4+r -> (half=qd, b=r); col=h
        #pragma unroll
        for (int r=0;r<4;r++){
          float hv = sigf(go[r]) * tanhf_( sigf(gi[r]) * tanhf_(gg[r]) );
          cct[r*10+w][h + 300*qd] = f2usr(hv);
        }
      }
    }
  }
  __syncthreads();

  // ---- P2: wp-MFMA  D[o 304][n 48] = W[304x608] @ cct[608x48]; 2 Mtiles/wave ----
  f32x4 acc[2][3];
  #pragma unroll
  for (int i=0;i<2;i++)
    #pragma unroll
    for (int nt=0;nt<3;nt++) acc[i][nt] = (f32x4){0.f,0.f,0.f,0.f};
  if (t>0){
    const u16* wbfA = (const u16*)((const unsigned*)wsf + OFF_WBF2);
    for (int ks=0; ks<19; ks++){
      const int kb = ks*32 + qd*8;
      s16x8 Bv[3];
      #pragma unroll
      for (int nt=0;nt<3;nt++)
        Bv[nt] = *(const s16x8*)&cct[nt*16+lo][kb];
      #pragma unroll
      for (int i=0;i<2;i++){
        int mt = w*2+i;
        if (mt<19){
          s16x8 Av = *(const s16x8*)(wbfA + ((size_t)(mt*19+ks)*64 + lane)*8);
          #pragma unroll
          for (int nt=0;nt<3;nt++)
            acc[i][nt] = __builtin_amdgcn_mfma_f32_16x16x32_bf16(Av, Bv[nt], acc[i][nt], 0,0,0);
        }
      }
    }
  }
  __syncthreads();   // all B-reads of cct done before hcat overwrite

  // ---- P2b (t>0): epilogue transpose: cct[n][o] = relu(D+bp) bf16, o<300 ----
  if (t>0){
    #pragma unroll
    for (int i=0;i<2;i++){
      int mt = w*2+i;
      if (mt<19 && (mt<18 || qd<3)){   // skip o in [300,304)
        int ob = mt*16 + qd*4;
        float p0=bp[ob], p1=bp[ob+1], p2=bp[ob+2], p3=bp[ob+3];
        #pragma unroll
        for (int nt=0;nt<3;nt++){
          int n = nt*16+lo;
          float v0=acc[i][nt][0]+p0, v1=acc[i][nt][1]+p1,
                v2=acc[i][nt][2]+p2, v3=acc[i][nt][3]+p3;
          unsigned w0 = ((unsigned)f2usr(v1>0.f?v1:0.f)<<16) | f2usr(v0>0.f?v0:0.f);
          unsigned w1 = ((unsigned)f2usr(v3>0.f?v3:0.f)<<16) | f2usr(v2>0.f?v2:0.f);
          *(unsigned*)&cct[n][ob]   = w0;
          *(unsigned*)&cct[n][ob+2] = w1;
        }
      }
    }
  }
  // ---- P3: htarget -> hcat cols [300,600); col 600 = 1.0 ----
  for (int p=tid; p<TB*300; p+=NTHR){
    int b=p/300, o=p%300;
    float ai=0.f, ag=0.f, ao=0.f;
    #pragma unroll
    for (int e=0;e<4;e++){
      float xv = exss[b][e];
      ai += wsf[OFF_WTP+(e*3+0)*300+o]*xv;
      ag += wsf[OFF_WTP+(e*3+1)*300+o]*xv;
      ao += wsf[OFF_WTP+(e*3+2)*300+o]*xv;
    }
    ai += wsf[OFF_BTP+o]; ag += wsf[OFF_BTP+300+o]; ao += wsf[OFF_BTP+600+o];
    u16 u = f2usr( sigf(ao)*tanhf_(sigf(ai)*tanhf_(ag)) );
    #pragma unroll
    for (int k=0;k<10;k++) cct[b*10+k][300+o] = u;
  }
  for (int p=tid; p<48*4; p+=NTHR){
    int n=p/4, c=p%4;
    ((unsigned*)&cct[n][600])[c] = (c==0)? 0x00003f80u : 0u;
  }
  __syncthreads();

  // ---- P5: store con1 tile [n 40][o 300] coalesced ----
  for (int p=tid; p<6000; p+=NTHR){
    int n=p/150, op=p%150;
    con1u[ ((size_t)(t*128+bt)*40 + n)*150 + op ] = *(const unsigned*)&cct[n][2*op];
  }

  // ---- P4: F1-MFMA  fc1[n 48][j 208] = hcat[48x608] @ F1[608x208]; nt in {w, w+10} ----
  f32x4 acc2[3][2];
  #pragma unroll
  for (int mt=0;mt<3;mt++)
    #pragma unroll
    for (int j=0;j<2;j++) acc2[mt][j] = (f32x4){0.f,0.f,0.f,0.f};
  {
    const u16* f1s = (const u16*)((const unsigned*)wsf + OFF_F1S);
    for (int ks=0; ks<19; ks++){
      const int kb = ks*32 + qd*8;
      s16x8 Am[3];
      #pragma unroll
      for (int mt=0;mt<3;mt++)
        Am[mt] = *(const s16x8*)&cct[mt*16+lo][kb];
      #pragma unroll
      for (int j=0;j<2;j++){
        int nt = w + j*NW;
        if (nt<13){
          s16x8 Bf = *(const s16x8*)(f1s + ((size_t)(nt*19+ks)*64 + lane)*8);
          #pragma unroll
          for (int mt=0;mt<3;mt++)
            acc2[mt][j] = __builtin_amdgcn_mfma_f32_16x16x32_bf16(Am[mt], Bf, acc2[mt][j], 0,0,0);
        }
      }
    }
  }
  // wdyn partials: relu(fc1)*F2, sum this wave's j-cols, reduce within quads
  {
    float f2c[2];
    #pragma unroll
    for (int j=0;j<2;j++){
      int nt = w + j*NW;
      int jj = nt*16+lo;
      f2c[j] = (nt<13 && jj<200)? F2[jj] : 0.f;
    }
    #pragma unroll
    for (int mt=0;mt<3;mt++)
      #pragma unroll
      for (int r=0;r<4;r++){
        float s = 0.f;
        #pragma unroll
        for (int j=0;j<2;j++){
          float v = acc2[mt][j][r];
          s += (v>0.f? v:0.f) * f2c[j];
        }
        s += __shfl_xor(s,1,64); s += __shfl_xor(s,2,64);
        s += __shfl_xor(s,4,64); s += __shfl_xor(s,8,64);
        if (lo==0) wdP[w][mt*16+qd*4+r] = s;
      }
  }
  __syncthreads();
  if (tid<40){
    int n=tid, b=n/10, k=n%10;
    float v = 0.f;
    #pragma unroll
    for (int ww=0;ww<NW;ww++) v += wdP[ww][n];
    float ang = fabsf(xse[b][1][k]-AngleM[k]) * (1.0f/360.0f);
    v += xse[b][0][k]*F2[200] + ang*F2[201] + b2[0];
    wdL[n] = v>0.f? v : 0.f;
  }
  __syncthreads();
  if (tid<TB){
    int b=tid;
    float m = wdL[b*10];
    #pragma unroll
    for (int k=1;k<10;k++) m = fmaxf(m, wdL[b*10+k]);
    float e[10]; float s=0.f;
    #pragma unroll
    for (int k=0;k<10;k++){ e[k]=__expf(wdL[b*10+k]-m); s+=e[k]; }
    float inv = 1.0f/s;
    #pragma unroll
    for (int k=0;k<10;k++) smg[t*5120 + k*512 + b0+b] = e[k]*inv;
  }
}

// ================= final: gather scramble, fuse, preds (10 waves) =================
__global__ __launch_bounds__(NTHR,3) void kern_final(
    const float* __restrict__ li, const float* __restrict__ ff,
    const float* __restrict__ bff, const float* __restrict__ fuse1,
    const float* __restrict__ biasf, const float* __restrict__ Wout,
    const float* __restrict__ biasout, const float* __restrict__ a,
    const float* wsf, const unsigned* __restrict__ con1u,
    float* __restrict__ outp)
{
  __shared__ unsigned conTu[40][152];   // [n][o-pairs]; u16 view stride 304
  __shared__ float xs17[TB][17][10];
  __shared__ float cats[TB][300];
  __shared__ float wa3s[TB][10];
  __shared__ float dss[TB][17];
  __shared__ float wAs[10];
  __shared__ float fup1[8][64], fup2[8][64];
  const int tid=threadIdx.x, t=blockIdx.y, bt=blockIdx.x, b0=bt*TB;
  for (int p=tid;p<TB*170;p+=NTHR){
    int b=p/170, r=p%170, f=r/10, k=r%10;
    xs17[b][f][k] = li[(((b0+b)*32+t)*28 + 11+f)*10 + k];
  }
  if (tid<10) wAs[tid] = wsf[OFF_WA+tid];
  for (int p=tid;p<6000;p+=NTHR){
    int n=p/150, op=p%150;
    conTu[n][op] = con1u[ ((size_t)(t*128+bt)*40 + n)*150 + op ];
  }
  __syncthreads();
  for (int p=tid;p<TB*10;p+=NTHR){
    int b=p/10, k=p%10;
    int g = (b0+b)*10+k;   // flat-reshape scramble of the [10,512] softmax matrix
    wa3s[b][k] = wsf[OFF_SM + t*5120 + (g>>9)*512 + (g&511)];
  }
  for (int p=tid;p<TB*17;p+=NTHR){
    int b=p/17, f=p%17; float s=0.f;
    #pragma unroll
    for (int k=0;k<10;k++) s += xs17[b][f][k]*wAs[k];
    dss[b][f]=s;
  }
  __syncthreads();
  const u16* conT = (const u16*)conTu;
  for (int p=tid;p<TB*300;p+=NTHR){
    int b=p/300, h=p%300;
    float s=0.f;
    #pragma unroll
    for (int k=0;k<10;k++)
      s += bfu(conT[(b*10+k)*304 + h]) * wa3s[b][k];
    cats[b][h]=s;
  }
  __syncthreads();
  const int w = tid>>6, lane = tid&63;
  const int o1 = lane;
  const bool o2v = lane<36;
  const int o2 = o2v ? (64+lane) : 99;
  if (w<8){   // fuse1 partials: wave = (b, half of h-range)
    int b=w>>1, half=w&1;
    float fu1 = half? 0.f : biasf[o1];
    float fu2 = half? 0.f : biasf[o2];
    const int hb = half*150;
    for (int h=hb; h<hb+150; h++){
      float cv = cats[b][h];
      fu1 += cv*fuse1[h*100+o1];
      fu2 += cv*fuse1[h*100+o2];
    }
    fup1[w][lane]=fu1; fup2[w][lane]=fu2;
  }
  __syncthreads();
  if (w<TB){
    const int b=w, bg=b0+b;
    const float aa = a[0], swa = wsf[OFF_SWA];
    float fu1 = fup1[2*b][lane] + fup1[2*b+1][lane];
    float fu2 = fup2[2*b][lane] + fup2[2*b+1][lane];
    float fd1 = bff[o1]*swa, fd2 = bff[o2]*swa;
    #pragma unroll
    for (int f=0;f<17;f++){
      float dv = dss[b][f];
      fd1 += ff[o1*17+f]*dv;
      fd2 += ff[o2*17+f]*dv;
    }
    float v = (aa*fu1+(1.f-aa)*fd1)*Wout[o1];
    if (o2v) v += (aa*fu2+(1.f-aa)*fd2)*Wout[o2];
    #pragma unroll
    for (int off=32;off>=1;off>>=1) v += __shfl_xor(v,off,64);
    if (lane==0) outp[t*512+bg] = v + biasout[0];
  }
}

__global__ void kernC(const float* __restrict__ labels, float* __restrict__ outp){
  int p = blockIdx.x*256 + threadIdx.x;
  if (p < 16384){
    int t=p>>9, b=p&511;
    outp[16384+p] = labels[b*32+t];
  }
}

// ================= weight prep =================
__global__ void kprep(const float* __restrict__ Wih, const float* __restrict__ b_ih,
                      const float* __restrict__ b_hh, const float* __restrict__ Wt,
                      const float* __restrict__ bt_ih, const float* __restrict__ bt_hh,
                      const float* __restrict__ wp, const float* __restrict__ F1,
                      const float* __restrict__ b1, float* __restrict__ wsf)
{
  int n = blockIdx.x*256 + threadIdx.x;
  if (n < 92416){   // wp A-frags: [mt][ks][lane][4 u32]
    int jp=n&3, lane=(n>>2)&63, rest=n>>8;
    int ks=rest%19, mt=rest/19;
    int m = mt*16 + (lane&15);
    int k = ks*32 + (lane>>4)*8 + 2*jp;
    float v0 = (m<300 && k  <600)? wp[m*600+k  ] : 0.f;
    float v1 = (m<300 && k+1<600)? wp[m*600+k+1] : 0.f;
    ((unsigned*)wsf)[OFF_WBF2+n] = ((unsigned)f2usr(v1)<<16) | f2usr(v0);
    return;
  }
  n -= 92416;
  if (n < 63232){   // F1 B-frags: [nt][ks][lane][4]; row 600 = b1
    int jp=n&3, lane=(n>>2)&63, rest=n>>8;
    int ks=rest%19, nt=rest/19;
    int col = nt*16 + (lane&15);
    int k = ks*32 + (lane>>4)*8 + 2*jp;
    float v0=0.f, v1=0.f;
    if (col<200){
      v0 = (k  <600)? F1[k*200+col]     : (k  ==600? b1[col] : 0.f);
      v1 = (k+1<600)? F1[(k+1)*200+col] : (k+1==600? b1[col] : 0.f);
    }
    ((unsigned*)wsf)[OFF_F1S+n] = ((unsigned)f2usr(v1)<<16) | f2usr(v0);
    return;
  }
  n -= 63232;
  if (n < 145920){  // cells B-frags: [k][ht][g][lane][4]; kk==11 -> bias (b_ih+b_hh)
    int jp=n&3, lane=(n>>2)&63, rest=n>>8;
    int g=rest%3, rest2=rest/3, ht=rest2%19, k=rest2/19;
    int h = ht*16 + (lane&15);
    int kk0 = (lane>>4)*8 + 2*jp;
    float v0=0.f, v1=0.f;
    if (h < 300){
      int G = h + (g==0?0:(g==1?600:900));
      v0 = (kk0<11)?   Wih[(k*1200+G)*11+kk0]
         : (kk0==11?   b_ih[k*1200+G]+b_hh[k*1200+G] : 0.f);
      int kk1 = kk0+1;
      v1 = (kk1<11)?   Wih[(k*1200+G)*11+kk1]
         : (kk1==11?   b_ih[k*1200+G]+b_hh[k*1200+G] : 0.f);
    }
    ((unsigned*)wsf)[OFF_WCELL+n] = ((unsigned)f2usr(v1)<<16) | f2usr(v0);
    return;
  }
  n -= 145920;
  if (n < 900){
    int h=n%300, g=n/300;
    int G = h + (g==0?0:(g==1?600:900));
    wsf[OFF_BTP+n] = bt_ih[G]+bt_hh[G]; return;
  }
  n -= 900;
  if (n < 3600){
    int h=n%300; int q=n/300; int g=q%3, e=q/3;
    int G = h + (g==0?0:(g==1?600:900));
    wsf[OFF_WTP+n] = Wt[G*4+e]; return;
  }
}

__global__ void kprep2(const float* __restrict__ DisM, float* __restrict__ wsf){
  if (threadIdx.x==0 && blockIdx.x==0){
    float m = DisM[0];
    for (int k=1;k<10;k++) m = fmaxf(m, DisM[k]);
    float e[10]; float s=0.f;
    for (int k=0;k<10;k++){ e[k]=__expf(DisM[k]-m); s+=e[k]; }
    float inv=1.0f/s; float sw=0.f;
    for (int k=0;k<10;k++){ float v=e[k]*inv; wsf[OFF_WA+k]=v; sw+=v; }
    wsf[OFF_SWA]=sw;
  }
}

extern "C" void kernel_launch(void* const* d_in, const int* in_sizes, int n_in,
                              void* d_out, int out_size, void* d_ws, size_t ws_size,
                              hipStream_t stream)
{
  const float* li     = (const float*)d_in[0];
  const float* labels = (const float*)d_in[1];
  const float* exs    = (const float*)d_in[2];
  const float* DisM   = (const float*)d_in[3];
  const float* AngleM = (const float*)d_in[4];
  const float* Wih    = (const float*)d_in[5];
  const float* b_ih   = (const float*)d_in[6];
  const float* b_hh   = (const float*)d_in[7];
  const float* Wt     = (const float*)d_in[8];
  const float* bt_ih  = (const float*)d_in[9];
  const float* bt_hh  = (const float*)d_in[10];
  const float* wp     = (const float*)d_in[11];
  const float* bp     = (const float*)d_in[12];
  const float* F1     = (const float*)d_in[13];
  const float* b1     = (const float*)d_in[14];
  const float* F2     = (const float*)d_in[15];
  const float* b2     = (const float*)d_in[16];
  const float* ff     = (const float*)d_in[17];
  const float* bff    = (const float*)d_in[18];
  const float* fuse1  = (const float*)d_in[19];
  const float* biasf  = (const float*)d_in[20];
  const float* Wout   = (const float*)d_in[21];
  const float* biasout= (const float*)d_in[22];
  const float* a      = (const float*)d_in[23];
  float* wsf = (float*)d_ws;
  float* outp = (float*)d_out;
  unsigned* con1u = (unsigned*)((char*)d_ws + CON1_BYTE);

  if (ws_size < WS_MIN_BYTES) return;  // proven available (R4 PATH1 ran)

  kprep<<<dim3(1196), dim3(256), 0, stream>>>(Wih,b_ih,b_hh,Wt,bt_ih,bt_hh,wp,F1,b1,wsf);
  kprep2<<<dim3(1), dim3(64), 0, stream>>>(DisM, wsf);
  kern_main <<<dim3(128,32), NTHR, 0, stream>>>(li, exs, AngleM, bp, F2, b2,
                                                wsf, con1u, wsf + OFF_SM);
  kern_final<<<dim3(128,32), NTHR, 0, stream>>>(li, ff, bff, fuse1, biasf, Wout, biasout, a,
                                                wsf, con1u, outp);
  kernC<<<dim3(64), dim3(256), 0, stream>>>(labels, outp);
}